// Round 4
// baseline (260.155 us; speedup 1.0000x reference)
//
#include <hip/hip_runtime.h>
#include <hip/hip_cooperative_groups.h>

namespace cg = cooperative_groups;

// Problem constants
#define N_ROWS   32768      // 64*512 flattened z rows
#define KCODES   1024
#define DDIM     256
#define RPB      64         // rows per argmin block: As=64KB -> 2 blocks/CU
#define NBLK     512        // 32768/64

// d_out float offsets (outputs concatenated in reference return order)
#define O_ZQ     0                    // 8388608
#define O_LOSS   8388608              // 1
#define O_IDX    8388609              // 32768
#define O_NCS    8421377              // 1024
#define O_NEA    8422401              // 262144
#define O_NEMB   8684545              // 262144

// workspace float offsets
#define W_ESUM   0                    // 262144 (zeroed in k_tail phase A)
#define W_CNT    262144               // 1024 ints (zeroed in k_prep2)
#define W_ENORM  263168               // 1024
#define W_LOSSP  264192               // 512
#define W_CUR    264704               // 1024 ints (unused since R4)
#define W_N      265728               // 1
#define W_IDX    265792               // 32768 ints
#define W_SORT   298560               // 32768 ints
#define W_RANK   331328               // 32768 ints (row's rank within its code)

typedef _Float16 half_t;
typedef __attribute__((ext_vector_type(8))) _Float16 half8;
typedef __attribute__((ext_vector_type(4))) float floatx4;

// ---------------------------------------------------------------------------
// Pack B into MFMA-native fragment order + compute ||e||^2.
// Layout (compact-addressing, R3): Bp[g16][pk][ns][lane][8]:
//   g16 = cq*4+g4 (wave-group, 16), pk = packed k-step (16: hi + lo-low-half;
//   phases 16..23 reuse pk 0..7), ns = 16-code subtile (4), lane
//   (col=lane&15, k=(lane>>4)*8+j). A wave-step's 4 ns loads span one
//   contiguous 4KB window -> single address reg + imm offsets in k_argmin.
// Block 0 also zeroes cnts (esum zeroing moved to k_tail phase A).
__global__ __launch_bounds__(256)
void k_prep2(const float* __restrict__ emb, float* __restrict__ enorm,
             half_t* __restrict__ Bp, int* __restrict__ cnts) {
    __shared__ half_t hi[16 * 256];
    __shared__ half_t lo[16 * 256];
    __shared__ float  ssum[256];
    const int ct  = blockIdx.x;       // 16-code tile
    const int tid = threadIdx.x;
    const int c16 = tid >> 4;         // code within tile
    const int dp  = tid & 15;         // 16-dim part

    if (ct == 0) {                    // zero cnts: 1024 ints = 256 int4
        int4 zz = {0, 0, 0, 0};
        ((int4*)cnts)[tid] = zz;
    }

    float ss = 0.f;
    #pragma unroll
    for (int i = 0; i < 4; ++i) {
        float4 v = *(const float4*)(emb + (size_t)(ct * 16 + c16) * DDIM + dp * 16 + i * 4);
        ss += v.x * v.x + v.y * v.y + v.z * v.z + v.w * v.w;
        #pragma unroll
        for (int q = 0; q < 4; ++q) {
            float f = (&v.x)[q];
            half_t h = (half_t)f;
            hi[c16 * 256 + dp * 16 + i * 4 + q] = h;
            lo[c16 * 256 + dp * 16 + i * 4 + q] = (half_t)(f - (float)h);
        }
    }
    ssum[tid] = ss;
    __syncthreads();
    if (tid < 16) {
        float s = 0.f;
        #pragma unroll
        for (int i = 0; i < 16; ++i) s += ssum[tid * 16 + i];
        enorm[ct * 16 + tid] = s;
    }

    // write phase: 16 packed steps x 64 lanes x 8 halfs
    const int g16 = ((ct >> 4) << 2) | ((ct >> 2) & 3);
    const int ns  = ct & 3;
    #pragma unroll
    for (int i = 0; i < 4; ++i) {
        int f    = tid + i * 256;     // 0..1023
        int ks   = f >> 6;            // pk 0..15
        int lane = f & 63;
        int cc   = lane & 15;
        int seg  = ks >> 3;           // 0:hi 1:lo
        int ko   = (ks & 7) * 32 + (lane >> 4) * 8;
        const half_t* src = (seg == 1) ? lo : hi;
        half8 v = *(const half8*)(src + cc * 256 + ko);
        *(half8*)(Bp + (((size_t)(g16 * 16 + ks) * 4 + ns) * 64 + lane) * 8) = v;
    }
}

// ---------------------------------------------------------------------------
// MFMA argmin. dist(r,c)=||e||^2-2 z.e; fp16 hi/lo K-concat (K'=768):
// phase c=0: z_hi.e_hi, c=1: z_hi.e_lo, c=2: z_lo.e_hi (B reuses pk 0..7).
// R4: depth-3 rotating prefetch (3 buffers, unroll 3: ~465 wave-cycles of
// L2-latency cover vs depth-2's ~165; VGPR 52->~70, still <=128 unified so
// 2 blocks/CU x 8 waves = 4 waves/SIMD holds). Stage-A store remapped to
// 8 rows x 8 slots per wave (conflict-free; was 32 lanes into one 512B row
// = 4-way, the source of R3's 3.16M conflict cycles).
// PLAIN __launch_bounds__(512) — NO min-waves arg, EVER (R5/R7/R8: the 2nd
// arg is a MINIMUM; allocator overshoots -> 64-VGPR cap -> 1.2GB spill).
__global__ __launch_bounds__(512)
void k_argmin(const float* __restrict__ z, const half_t* __restrict__ Bp,
              const float* __restrict__ enorm, const float* __restrict__ embf,
              int* __restrict__ out_idx, float* __restrict__ out_idx_f,
              float* __restrict__ out_zq, float* __restrict__ lossp,
              int* __restrict__ counts_i, int* __restrict__ rank_ws) {
    __shared__ __align__(16) half_t As[RPB * 512];   // 64 KB

    const int tid  = threadIdx.x;
    const int w    = tid >> 6;        // 0..7
    const int lane = tid & 63;
    const int tx   = lane & 15;
    const int quad = lane >> 4;
    const int rh   = w >> 2;          // row half: 0 -> rows 0..31, 1 -> 32..63
    const int cq   = w & 3;           // code quarter: codes [cq*256, cq*256+256)
    const int rbase = blockIdx.x * RPB;

    // ---- stage A: read z fp32, split hi/lo in-register, swizzled LDS store.
    // Wave covers 8 rows x 8 g-slots per iteration: conflict-free stores
    // (8 bank-quads x 8 rows, 2 lanes/bank), global reads 8x256B segments.
    {
        const int arow = w * 8 + (lane >> 3);   // 0..63, wave-local 8 rows
        const int sw   = arow & 7;              // == lane>>3
        #pragma unroll
        for (int it = 0; it < 4; ++it) {
            int g = it * 8 + (lane & 7);        // 0..31
            const float* zp = z + (size_t)(rbase + arow) * DDIM + g * 8;
            float4 v0 = *(const float4*)zp;
            float4 v1 = *(const float4*)(zp + 4);
            half8 hi, lo;
            hi[0] = (half_t)v0.x; lo[0] = (half_t)(v0.x - (float)hi[0]);
            hi[1] = (half_t)v0.y; lo[1] = (half_t)(v0.y - (float)hi[1]);
            hi[2] = (half_t)v0.z; lo[2] = (half_t)(v0.z - (float)hi[2]);
            hi[3] = (half_t)v0.w; lo[3] = (half_t)(v0.w - (float)hi[3]);
            hi[4] = (half_t)v1.x; lo[4] = (half_t)(v1.x - (float)hi[4]);
            hi[5] = (half_t)v1.y; lo[5] = (half_t)(v1.y - (float)hi[5]);
            hi[6] = (half_t)v1.z; lo[6] = (half_t)(v1.z - (float)hi[6]);
            hi[7] = (half_t)v1.w; lo[7] = (half_t)(v1.w - (float)hi[7]);
            *(half8*)(&As[arow * 512 + ((g ^ sw)) * 8])        = hi;  // k8 = g
            *(half8*)(&As[arow * 512 + (((32 + g) ^ sw)) * 8]) = lo;  // k8 = 32+g
        }
    }
    __syncthreads();                  // the ONLY main-loop barrier

    floatx4 zero4 = {0.f, 0.f, 0.f, 0.f};
    float bd[2][4];
    int   bi[2][4];
    #pragma unroll
    for (int mt = 0; mt < 2; ++mt)
        #pragma unroll
        for (int r = 0; r < 4; ++r) { bd[mt][r] = 3.402823466e38f; bi[mt][r] = 0; }

    for (int g4 = 0; g4 < 4; ++g4) {
        const int cb = cq * 256 + g4 * 64;
        // compact layout: g16 = cq*4+g4; Bg + pk*2048 + ns*512 (halfs)
        const half_t* Bg = Bp + (size_t)(cq * 4 + g4) * 32768 + (size_t)lane * 8;

        floatx4 acc[2][4];
        #pragma unroll
        for (int mt = 0; mt < 2; ++mt)
            #pragma unroll
            for (int ns = 0; ns < 4; ++ns) acc[mt][ns] = zero4;

        half8 B0[4], B1[4], B2[4];
        #define LOADB(PK, BUF)                                                 \
            { const half_t* bp_ = Bg + (PK) * 2048;                            \
              _Pragma("unroll")                                                \
              for (int ns = 0; ns < 4; ++ns)                                   \
                  BUF[ns] = *(const half8*)(bp_ + ns * 512); }
        #define MFMA_BLK(BUF)                                                  \
            _Pragma("unroll")                                                  \
            for (int mt = 0; mt < 2; ++mt)                                     \
                _Pragma("unroll")                                              \
                for (int ns = 0; ns < 4; ++ns)                                 \
                    acc[mt][ns] = __builtin_amdgcn_mfma_f32_16x16x32_f16(      \
                        a[mt], BUF[ns], acc[mt][ns], 0, 0, 0);

        LOADB(0, B0);
        LOADB(1, B1);
        LOADB(2, B2);

        #pragma unroll 3
        for (int ks = 0; ks < 24; ++ks) {
            // phases 0..15 read pk=ks; 16..23 reuse pk 0..7 (k8 base 32 = z_lo)
            const int k8b = ((ks & 16) << 1) + (ks & 7) * 4;
            half8 a[2];
            #pragma unroll
            for (int mt = 0; mt < 2; ++mt) {
                int row = rh * 32 + mt * 16 + tx;
                a[mt] = *(half8*)(&As[row * 512 + ((k8b + quad) ^ (row & 7)) * 8]);
            }
            const int m3 = ks % 3;    // static under unroll 3
            if (m3 == 0) {
                MFMA_BLK(B0)
                if (ks + 3 < 24) { LOADB((ks + 3) & 15, B0); }
            } else if (m3 == 1) {
                MFMA_BLK(B1)
                if (ks + 3 < 24) { LOADB((ks + 3) & 15, B1); }
            } else {
                MFMA_BLK(B2)
                if (ks + 3 < 24) { LOADB((ks + 3) & 15, B2); }
            }
        }
        #undef LOADB
        #undef MFMA_BLK

        // fold group into running argmin (codes ascending; strict <, min-index)
        #pragma unroll
        for (int ns = 0; ns < 4; ++ns) {
            float en = enorm[cb + ns * 16 + tx];
            int   cc = cb + ns * 16 + tx;
            #pragma unroll
            for (int mt = 0; mt < 2; ++mt)
                #pragma unroll
                for (int r = 0; r < 4; ++r) {
                    float d = fmaf(-2.f, acc[mt][ns][r], en);
                    if (d < bd[mt][r]) { bd[mt][r] = d; bi[mt][r] = cc; }
                }
        }
    }

    // reduce across 16 tx lanes (same row, different codes); ties -> min index
    #pragma unroll
    for (int mt = 0; mt < 2; ++mt)
        #pragma unroll
        for (int r = 0; r < 4; ++r) {
            float d = bd[mt][r];
            int   b = bi[mt][r];
            #pragma unroll
            for (int off = 8; off > 0; off >>= 1) {
                float od = __shfl_xor(d, off);
                int   ob = __shfl_xor(b, off);
                if (od < d || (od == d && ob < b)) { d = od; b = ob; }
            }
            bd[mt][r] = d; bi[mt][r] = b;
        }

    // cross-wave reduce via LDS (reuse As): per row, 4 code-quarter candidates
    __syncthreads();
    float* sd   = (float*)As;          // [64 rows][4 quarters]
    int*   si   = ((int*)As) + 256;
    int*   sidx = ((int*)As) + 512;    // final idx per row
    if (tx == 0) {
        #pragma unroll
        for (int mt = 0; mt < 2; ++mt)
            #pragma unroll
            for (int r = 0; r < 4; ++r) {
                int row = rh * 32 + mt * 16 + quad * 4 + r;  // C-layout: row = quad*4+reg
                sd[row * 4 + cq] = bd[mt][r];
                si[row * 4 + cq] = bi[mt][r];
            }
    }
    __syncthreads();
    if (tid < RPB) {
        int row = tid;
        float d = sd[row * 4];
        int   b = si[row * 4];
        #pragma unroll
        for (int ww = 1; ww < 4; ++ww) {
            float od = sd[row * 4 + ww];
            int   ob = si[row * 4 + ww];
            if (od < d || (od == d && ob < b)) { d = od; b = ob; }
        }
        sidx[row] = b;
        out_idx[rbase + row]   = b;
        out_idx_f[rbase + row] = (float)b;
        int rk = atomicAdd(&counts_i[b], 1);   // rank of this row within code b
        rank_ws[rbase + row] = rk;
    }
    __syncthreads();

    // ---- fused z_q epilogue: z_q_st write + commitment-loss partial
    float l = 0.f;
    #pragma unroll
    for (int u = 0; u < 8; ++u) {
        int gi  = tid + u * 512;       // 0..4095 float4s = 64 rows x 64
        int row = gi >> 6;
        int c4  = gi & 63;
        int k   = sidx[row];           // wave-uniform
        float4 zv = *(const float4*)(z    + (size_t)(rbase + row) * DDIM + c4 * 4);
        float4 ev = *(const float4*)(embf + (size_t)k * DDIM + c4 * 4);
        float dx = ev.x - zv.x, dy = ev.y - zv.y, dz = ev.z - zv.z, dw = ev.w - zv.w;
        float4 o = { zv.x + dx, zv.y + dy, zv.z + dz, zv.w + dw };  // z + (z_q - z)
        *(float4*)(out_zq + (size_t)(rbase + row) * DDIM + c4 * 4) = o;
        l += dx * dx + dy * dy + dz * dz + dw * dw;
    }
    #pragma unroll
    for (int off = 32; off > 0; off >>= 1) l += __shfl_down(l, off);
    __shared__ float ls[8];
    if (lane == 0) ls[w] = l;
    __syncthreads();
    if (tid == 0) {
        float s = 0.f;
        #pragma unroll
        for (int i = 0; i < 8; ++i) s += ls[i];
        lossp[blockIdx.x] = s;
    }
}

// ---------------------------------------------------------------------------
// Cooperative tail: scan + rank + segment-sum + embed in ONE kernel
// (256 blocks x 256 thr, all co-resident; 2 grid syncs replace 3 kernel
// boundaries; rank is atomic-free: pos = base[k] + rank_ws[r]).
__global__ __launch_bounds__(256)
void k_tail(const float* __restrict__ cs_in, const int* __restrict__ counts_i,
            const float* __restrict__ lossp, const int* __restrict__ idx,
            const int* __restrict__ rank_ws, const float* __restrict__ z,
            const float* __restrict__ ea,
            float* __restrict__ out_ncs, float* __restrict__ n_ws,
            float* __restrict__ loss_out, int* __restrict__ rows_sorted,
            float* __restrict__ esum, float* __restrict__ out_nea,
            float* __restrict__ out_nemb) {
    cg::grid_group grid = cg::this_grid();
    const int tid = threadIdx.x;
    const int bid = blockIdx.x;

    __shared__ int ps[256];
    __shared__ int base_s[1024];
    __shared__ float sv[4], sl[4];

    // ---- Phase A: zero esum (65536 float4 == 256 blk x 256 thr, 1 each)
    {
        float4 z4 = {0.f, 0.f, 0.f, 0.f};
        ((float4*)esum)[bid * 256 + tid] = z4;
    }
    // redundant per-block scan of counts -> base_s[1024]
    int c[4]; int pt = 0;
    #pragma unroll
    for (int i = 0; i < 4; ++i) { c[i] = counts_i[tid * 4 + i]; pt += c[i]; }
    ps[tid] = pt;
    __syncthreads();
    for (int s = 1; s < 256; s <<= 1) {
        int v = (tid >= s) ? ps[tid - s] : 0;
        __syncthreads();
        ps[tid] += v;
        __syncthreads();
    }
    int o = ps[tid] - pt;              // exclusive base for this thread's 4 bins
    float v = 0.f;
    #pragma unroll
    for (int i = 0; i < 4; ++i) {
        base_s[tid * 4 + i] = o;
        o += c[i];
        if (bid == 0) {
            float nc = cs_in[tid * 4 + i] * 0.99f + 0.01f * (float)c[i];
            out_ncs[tid * 4 + i] = nc;
            v += nc;
        }
    }
    if (bid == 0) {                    // n + loss finalization (block 0 only)
        float l = 0.f;
        for (int i = tid; i < NBLK; i += 256) l += lossp[i];
        #pragma unroll
        for (int off = 32; off > 0; off >>= 1) {
            v += __shfl_down(v, off);
            l += __shfl_down(l, off);
        }
        if ((tid & 63) == 0) { sv[tid >> 6] = v; sl[tid >> 6] = l; }
        __syncthreads();
        if (tid == 0) {
            n_ws[0]     = sv[0] + sv[1] + sv[2] + sv[3];
            loss_out[0] = 0.25f * ((sl[0] + sl[1] + sl[2] + sl[3]) / 8388608.0f);
        }
    }
    __syncthreads();                   // base_s ready
    // rank this block's 128-row slice (atomic-free)
    if (tid < 128) {
        int r = bid * 128 + tid;
        int k = idx[r];
        rows_sorted[base_s[k] + rank_ws[r]] = r;
    }

    grid.sync();

    // ---- Phase C: skew-proof segment-sum (4 waves x 32 sorted positions)
    {
        const int w    = tid >> 6;     // 0..3
        const int lane = tid & 63;
        const int base = (bid * 4 + w) * 32;   // 256 blk x 4 waves x 32 = 32768
        int r = rows_sorted[base + (lane & 31)];
        int cc = idx[r];
        float4 acc = {0.f, 0.f, 0.f, 0.f};
        #pragma unroll 8
        for (int j = 0; j < 32; ++j) {
            int rj = __shfl(r, j);
            int cj = __shfl(cc, j);
            float4 zv = *(const float4*)(z + (size_t)rj * DDIM + lane * 4);
            acc.x += zv.x; acc.y += zv.y; acc.z += zv.z; acc.w += zv.w;
            int cn = (j < 31) ? __shfl(cc, j + 1) : -1;
            if (cn != cj) {            // wave-uniform branch
                float* p = esum + (size_t)cj * DDIM + lane * 4;
                atomicAdd(p + 0, acc.x);
                atomicAdd(p + 1, acc.y);
                atomicAdd(p + 2, acc.z);
                atomicAdd(p + 3, acc.w);
                acc.x = 0.f; acc.y = 0.f; acc.z = 0.f; acc.w = 0.f;
            }
        }
    }

    grid.sync();

    // ---- Phase D: embed (4 codes per block, 256 dims per thread pass)
    {
        float nv = n_ws[0];
        #pragma unroll
        for (int i = 0; i < 4; ++i) {
            int k = bid * 4 + i;
            size_t off = (size_t)k * DDIM + tid;
            float nea = ea[off] * 0.99f + 0.01f * esum[off];
            out_nea[off] = nea;
            float ncv = cs_in[k] * 0.99f + 0.01f * (float)counts_i[k];
            float csv = (ncv + 1e-6f) / (nv + 0.001024f);   // (ncs+eps)/(n+K*eps)
            out_nemb[off] = nea / csv;
        }
    }
}

// ---------------------------------------------------------------------------
extern "C" void kernel_launch(void* const* d_in, const int* in_sizes, int n_in,
                              void* d_out, int out_size, void* d_ws, size_t ws_size,
                              hipStream_t stream) {
    const float* z   = (const float*)d_in[0];
    const float* emb = (const float*)d_in[1];
    const float* cs  = (const float*)d_in[2];
    const float* ea  = (const float*)d_in[3];
    float* out = (float*)d_out;
    float* ws  = (float*)d_ws;

    float* esum    = ws + W_ESUM;
    int*   cnts    = (int*)(ws + W_CNT);
    float* enorm   = ws + W_ENORM;
    float* lossp   = ws + W_LOSSP;
    float* wn      = ws + W_N;
    int*   widx    = (int*)(ws + W_IDX);
    int*   rsorted = (int*)(ws + W_SORT);
    int*   rankw   = (int*)(ws + W_RANK);

    // packed-B fp16 scratch in dead O_NEA output region (16B-aligned;
    // k_tail phase D, the only writer of that region, runs last). 1MB.
    half_t* Bp = (half_t*)(out + O_NEA + 3);   // 524288 halfs

    k_prep2  <<<64, 256, 0, stream>>>(emb, enorm, Bp, cnts);
    k_argmin <<<NBLK, 512, 0, stream>>>(z, Bp, enorm, emb,
                                        widx, out + O_IDX, out + O_ZQ, lossp,
                                        cnts, rankw);

    // cooperative tail: scan+rank+esum+embed with 2 grid syncs
    float* o_ncs  = out + O_NCS;
    float* o_loss = out + O_LOSS;
    float* o_nea  = out + O_NEA;
    float* o_nemb = out + O_NEMB;
    void* args[] = {
        (void*)&cs, (void*)&cnts, (void*)&lossp, (void*)&widx, (void*)&rankw,
        (void*)&z, (void*)&ea,
        (void*)&o_ncs, (void*)&wn, (void*)&o_loss, (void*)&rsorted,
        (void*)&esum, (void*)&o_nea, (void*)&o_nemb
    };
    hipLaunchCooperativeKernel((const void*)k_tail, dim3(256), dim3(256),
                               args, 0, stream);
}